// Round 1
// baseline (325.718 us; speedup 1.0000x reference)
//
#include <hip/hip_runtime.h>
#include <math.h>

#define BB 2
#define CC 32
#define C8 4
#define NN 4096

// ---------------- Kernel A: QKV projections ----------------
// thread = (b, n). q,k: [B][C8][N], v: [B][C][N]
__global__ __launch_bounds__(256) void kproj(const float* __restrict__ x,
    const float* __restrict__ wq, const float* __restrict__ bq,
    const float* __restrict__ wk, const float* __restrict__ bk,
    const float* __restrict__ wv, const float* __restrict__ bv,
    float* __restrict__ q, float* __restrict__ k, float* __restrict__ v)
{
    __shared__ float swq[C8*CC], swk[C8*CC], swv[CC*CC], sbq[C8], sbk[C8], sbv[CC];
    int tid = threadIdx.x;
    for (int i = tid; i < C8*CC; i += 256) { swq[i] = wq[i]; swk[i] = wk[i]; }
    for (int i = tid; i < CC*CC; i += 256) swv[i] = wv[i];
    if (tid < C8) { sbq[tid] = bq[tid]; sbk[tid] = bk[tid]; }
    if (tid < CC) sbv[tid] = bv[tid];
    __syncthreads();
    int g = blockIdx.x*256 + tid;         // 0..8191
    int b = g >> 12; int n = g & (NN-1);
    const float* xb = x + (size_t)b*CC*NN + n;
    float xr[CC];
    #pragma unroll
    for (int c = 0; c < CC; ++c) xr[c] = xb[(size_t)c*NN];
    #pragma unroll
    for (int o = 0; o < C8; ++o) {
        float aq = sbq[o], ak = sbk[o];
        #pragma unroll
        for (int c = 0; c < CC; ++c) { aq += swq[o*CC+c]*xr[c]; ak += swk[o*CC+c]*xr[c]; }
        q[((size_t)b*C8+o)*NN + n] = aq;
        k[((size_t)b*C8+o)*NN + n] = ak;
    }
    #pragma unroll
    for (int o = 0; o < CC; ++o) {
        float av = sbv[o];
        #pragma unroll
        for (int c = 0; c < CC; ++c) av += swv[o*CC+c]*xr[c];
        v[((size_t)b*CC+o)*NN + n] = av;
    }
}

// ---------------- Kernel B1: CAM gram matrix ----------------
// one wave per (b,c,d): eng[b,c,d] = dot(x[b,c,:], x[b,d,:])
__global__ __launch_bounds__(256) void keng(const float* __restrict__ x, float* __restrict__ eng)
{
    int w = threadIdx.x >> 6, lane = threadIdx.x & 63;
    int p = blockIdx.x*4 + w;             // 0..2047
    int b = p >> 10, c = (p >> 5) & 31, d = p & 31;
    const float4* xc = (const float4*)(x + ((size_t)b*CC + c)*NN);
    const float4* xd = (const float4*)(x + ((size_t)b*CC + d)*NN);
    float s = 0.f;
    for (int t = lane; t < NN/4; t += 64) {
        float4 a = xc[t], bb = xd[t];
        s += a.x*bb.x + a.y*bb.y + a.z*bb.z + a.w*bb.w;
    }
    #pragma unroll
    for (int off = 32; off; off >>= 1) s += __shfl_down(s, off, 64);
    if (lane == 0) eng[p] = s;
}

// ---------------- Kernel B2: cattn softmax + fold into Wx ----------------
// softmax(max-eng) over d == exp(rowmin - eng)/sum.
// Wx[b][o][d] = wo[o][d] + wo[o][32+d] + gc * sum_c wo[o][32+c]*cattn[b][c][d]
__global__ __launch_bounds__(256) void kwx(const float* __restrict__ eng,
    const float* __restrict__ wo, const float* __restrict__ gc,
    float* __restrict__ wx)
{
    __shared__ float se[CC*CC], sc[CC*CC];
    int b = blockIdx.x, tid = threadIdx.x;
    for (int i = tid; i < CC*CC; i += 256) se[i] = eng[b*CC*CC + i];
    __syncthreads();
    if (tid < CC) {
        float mn = se[tid*CC];
        #pragma unroll
        for (int d = 1; d < CC; ++d) mn = fminf(mn, se[tid*CC+d]);
        float pv[CC]; float s = 0.f;
        #pragma unroll
        for (int d = 0; d < CC; ++d) { pv[d] = __expf(mn - se[tid*CC+d]); s += pv[d]; }
        float inv = 1.f/s;
        #pragma unroll
        for (int d = 0; d < CC; ++d) sc[tid*CC+d] = pv[d]*inv;
    }
    __syncthreads();
    float g = gc[0];
    for (int i = tid; i < CC*CC; i += 256) {
        int o = i >> 5, d = i & 31;
        float acc = wo[o*64 + d] + wo[o*64 + 32 + d];
        float t = 0.f;
        #pragma unroll
        for (int c2 = 0; c2 < CC; ++c2) t += wo[o*64 + 32 + c2] * sc[c2*CC + d];
        wx[b*CC*CC + i] = acc + g * t;
    }
}

// ---------------- Kernel C: split-j flash PAM partials ----------------
// grid = B * 64(i-tiles) * 4(j-groups) = 512 blocks, 256 thr = 4 waves.
// lane = query i; wave handles 256 j's. No max-subtraction needed (|e| <~ 12).
// Block-combines 4 wave partials -> part[b][jg][f][n], f=0..31 acc, f=32 sumexp.
__global__ __launch_bounds__(256) void kflash(const float* __restrict__ q,
    const float* __restrict__ k, const float* __restrict__ v,
    float* __restrict__ part)
{
    int blk = blockIdx.x;
    int b = blk >> 8;
    int r = blk & 255;
    int it = r >> 2;             // 0..63
    int jg = r & 3;              // 0..3
    int w = threadIdx.x >> 6, lane = threadIdx.x & 63;
    int i = it*64 + lane;

    const float* qb = q + (size_t)b*C8*NN;
    float q0 = qb[i], q1 = qb[NN+i], q2 = qb[2*NN+i], q3 = qb[3*NN+i];
    const float4* k0 = (const float4*)(k + (size_t)b*C8*NN);
    const float4* vb = (const float4*)(v + (size_t)b*CC*NN);

    float acc[CC];
    #pragma unroll
    for (int c = 0; c < CC; ++c) acc[c] = 0.f;
    float se = 0.f;

    int jq0 = (jg*1024 + w*256) >> 2;     // float4 index
    for (int j = jq0; j < jq0 + 64; ++j) {
        float4 ka = k0[j], kb = k0[NN/4 + j], kc = k0[2*(NN/4) + j], kd = k0[3*(NN/4) + j];
        float e0 = q0*ka.x + q1*kb.x + q2*kc.x + q3*kd.x;
        float e1 = q0*ka.y + q1*kb.y + q2*kc.y + q3*kd.y;
        float e2 = q0*ka.z + q1*kb.z + q2*kc.z + q3*kd.z;
        float e3 = q0*ka.w + q1*kb.w + q2*kc.w + q3*kd.w;
        float p0 = __expf(e0), p1 = __expf(e1), p2 = __expf(e2), p3 = __expf(e3);
        se += (p0+p1)+(p2+p3);
        #pragma unroll
        for (int c = 0; c < CC; ++c) {
            float4 vv = vb[(size_t)c*(NN/4) + j];
            acc[c] += p0*vv.x + p1*vv.y + p2*vv.z + p3*vv.w;
        }
    }

    __shared__ float sp[4][64][33];
    #pragma unroll
    for (int c = 0; c < CC; ++c) sp[w][lane][c] = acc[c];
    sp[w][lane][32] = se;
    __syncthreads();
    if (threadIdx.x < 64) {
        int qi = threadIdx.x;
        float* dst = part + (((size_t)b*4 + jg)*33)*NN + it*64 + qi;
        #pragma unroll
        for (int f = 0; f < 33; ++f) {
            float s = sp[0][qi][f] + sp[1][qi][f] + sp[2][qi][f] + sp[3][qi][f];
            dst[(size_t)f*NN] = s;
        }
    }
}

// ---------------- Kernel D: combine partials + output projection ----------------
// thread = (b, n). out[o,n] = sum_c gp*wo[o,c]*pam[c] + sum_d Wx[o,d]*x[d,n] + bo[o]
__global__ __launch_bounds__(256) void kout(const float* __restrict__ part,
    const float* __restrict__ x, const float* __restrict__ wo,
    const float* __restrict__ bo, const float* __restrict__ gp,
    const float* __restrict__ wx, float* __restrict__ out)
{
    __shared__ float sw1[CC*CC], swx[CC*CC], sbo[CC];
    int blk = blockIdx.x;
    int b = blk >> 4;                   // 16 blocks per batch
    int n = (blk & 15)*256 + threadIdx.x;
    float g = gp[0];
    for (int i = threadIdx.x; i < CC*CC; i += 256) {
        int o = i >> 5, c2 = i & 31;
        sw1[i] = g * wo[o*64 + c2];
        swx[i] = wx[b*CC*CC + i];
    }
    if (threadIdx.x < CC) sbo[threadIdx.x] = bo[threadIdx.x];
    __syncthreads();

    const float* pb = part + (size_t)b*4*33*NN + n;
    float acc[CC]; float se = 0.f;
    #pragma unroll
    for (int c = 0; c < CC; ++c) acc[c] = 0.f;
    #pragma unroll
    for (int jg = 0; jg < 4; ++jg) {
        const float* p = pb + (size_t)jg*33*NN;
        #pragma unroll
        for (int f = 0; f < CC; ++f) acc[f] += p[(size_t)f*NN];
        se += p[(size_t)32*NN];
    }
    float inv = 1.f/se;
    float o_[CC];
    #pragma unroll
    for (int o = 0; o < CC; ++o) o_[o] = sbo[o];
    #pragma unroll
    for (int c = 0; c < CC; ++c) {
        float pc = acc[c]*inv;
        #pragma unroll
        for (int o = 0; o < CC; ++o) o_[o] += sw1[o*CC+c]*pc;
    }
    const float* xb = x + (size_t)b*CC*NN + n;
    #pragma unroll
    for (int d = 0; d < CC; ++d) {
        float xd = xb[(size_t)d*NN];
        #pragma unroll
        for (int o = 0; o < CC; ++o) o_[o] += swx[o*CC+d]*xd;
    }
    float* ob = out + (size_t)b*CC*NN + n;
    #pragma unroll
    for (int o = 0; o < CC; ++o) ob[(size_t)o*NN] = o_[o];
}

extern "C" void kernel_launch(void* const* d_in, const int* in_sizes, int n_in,
                              void* d_out, int out_size, void* d_ws, size_t ws_size,
                              hipStream_t stream)
{
    const float* x  = (const float*)d_in[0];
    const float* wq = (const float*)d_in[1];
    const float* bq = (const float*)d_in[2];
    const float* wk = (const float*)d_in[3];
    const float* bk = (const float*)d_in[4];
    const float* wv = (const float*)d_in[5];
    const float* bv = (const float*)d_in[6];
    const float* gp = (const float*)d_in[7];
    const float* gc = (const float*)d_in[8];
    const float* wo = (const float*)d_in[9];
    const float* bo = (const float*)d_in[10];

    float* ws   = (float*)d_ws;
    float* q    = ws;                 // B*C8*N      = 32768
    float* k    = q + 32768;          // 32768
    float* v    = k + 32768;          // B*C*N       = 262144
    float* eng  = v + 262144;         // B*C*C       = 2048
    float* wx   = eng + 2048;         // 2048
    float* part = wx + 2048;          // B*4*33*N    = 1081344  (~5.7 MB total)

    kproj<<<32, 256, 0, stream>>>(x, wq, bq, wk, bk, wv, bv, q, k, v);
    keng<<<512, 256, 0, stream>>>(x, eng);
    kwx<<<BB, 256, 0, stream>>>(eng, wo, gc, wx);
    kflash<<<512, 256, 0, stream>>>(q, k, v, part);
    kout<<<32, 256, 0, stream>>>(part, x, wo, bo, gp, wx, (float*)d_out);
}

// Round 2
// 66.634 us; speedup vs baseline: 4.8881x; 4.8881x over previous
//
#include <hip/hip_runtime.h>
#include <hip/hip_bf16.h>
#include <math.h>

#define BB 2
#define CC 32
#define C8 4
#define NN 4096

typedef __attribute__((ext_vector_type(8))) short short8;
typedef __attribute__((ext_vector_type(4))) float f32x4;

static __device__ __forceinline__ short f2bf(float x) {
    return __builtin_bit_cast(short, __float2bfloat16(x));
}

// ---------------- Kernel A: QKV projections ----------------
// thread = (b, n). q,k: f32 [B][C8][N]; v: bf16 [B][C][N]
__global__ __launch_bounds__(256) void kproj(const float* __restrict__ x,
    const float* __restrict__ wq, const float* __restrict__ bq,
    const float* __restrict__ wk, const float* __restrict__ bk,
    const float* __restrict__ wv, const float* __restrict__ bv,
    float* __restrict__ q, float* __restrict__ k, short* __restrict__ vbf)
{
    __shared__ float swq[C8*CC], swk[C8*CC], swv[CC*CC], sbq[C8], sbk[C8], sbv[CC];
    int tid = threadIdx.x;
    for (int i = tid; i < C8*CC; i += 256) { swq[i] = wq[i]; swk[i] = wk[i]; }
    for (int i = tid; i < CC*CC; i += 256) swv[i] = wv[i];
    if (tid < C8) { sbq[tid] = bq[tid]; sbk[tid] = bk[tid]; }
    if (tid < CC) sbv[tid] = bv[tid];
    __syncthreads();
    int g = blockIdx.x*256 + tid;         // 0..8191
    int b = g >> 12; int n = g & (NN-1);
    const float* xb = x + (size_t)b*CC*NN + n;
    float xr[CC];
    #pragma unroll
    for (int c = 0; c < CC; ++c) xr[c] = xb[(size_t)c*NN];
    #pragma unroll
    for (int o = 0; o < C8; ++o) {
        float aq = sbq[o], ak = sbk[o];
        #pragma unroll
        for (int c = 0; c < CC; ++c) { aq += swq[o*CC+c]*xr[c]; ak += swk[o*CC+c]*xr[c]; }
        q[((size_t)b*C8+o)*NN + n] = aq;
        k[((size_t)b*C8+o)*NN + n] = ak;
    }
    #pragma unroll
    for (int o = 0; o < CC; ++o) {
        float av = sbv[o];
        #pragma unroll
        for (int c = 0; c < CC; ++c) av += swv[o*CC+c]*xr[c];
        vbf[((size_t)b*CC+o)*NN + n] = f2bf(av);
    }
}

// ---------------- Kernel B1: CAM gram matrix ----------------
__global__ __launch_bounds__(256) void keng(const float* __restrict__ x, float* __restrict__ eng)
{
    int w = threadIdx.x >> 6, lane = threadIdx.x & 63;
    int p = blockIdx.x*4 + w;             // 0..2047
    int b = p >> 10, c = (p >> 5) & 31, d = p & 31;
    const float4* xc = (const float4*)(x + ((size_t)b*CC + c)*NN);
    const float4* xd = (const float4*)(x + ((size_t)b*CC + d)*NN);
    float s = 0.f;
    for (int t = lane; t < NN/4; t += 64) {
        float4 a = xc[t], bb = xd[t];
        s += a.x*bb.x + a.y*bb.y + a.z*bb.z + a.w*bb.w;
    }
    #pragma unroll
    for (int off = 32; off; off >>= 1) s += __shfl_down(s, off, 64);
    if (lane == 0) eng[p] = s;
}

// ---------------- Kernel B2: cattn softmax + fold into Wx ----------------
__global__ __launch_bounds__(256) void kwx(const float* __restrict__ eng,
    const float* __restrict__ wo, const float* __restrict__ gc,
    float* __restrict__ wx)
{
    __shared__ float se[CC*CC], sc[CC*CC];
    int b = blockIdx.x, tid = threadIdx.x;
    for (int i = tid; i < CC*CC; i += 256) se[i] = eng[b*CC*CC + i];
    __syncthreads();
    if (tid < CC) {
        float mn = se[tid*CC];
        #pragma unroll
        for (int d = 1; d < CC; ++d) mn = fminf(mn, se[tid*CC+d]);
        float pv[CC]; float s = 0.f;
        #pragma unroll
        for (int d = 0; d < CC; ++d) { pv[d] = __expf(mn - se[tid*CC+d]); s += pv[d]; }
        float inv = 1.f/s;
        #pragma unroll
        for (int d = 0; d < CC; ++d) sc[tid*CC+d] = pv[d]*inv;
    }
    __syncthreads();
    float g = gc[0];
    for (int i = tid; i < CC*CC; i += 256) {
        int o = i >> 5, d = i & 31;
        float acc = wo[o*64 + d] + wo[o*64 + 32 + d];
        float t = 0.f;
        #pragma unroll
        for (int c2 = 0; c2 < CC; ++c2) t += wo[o*64 + 32 + c2] * sc[c2*CC + d];
        wx[b*CC*CC + i] = acc + g * t;
    }
}

// ---------------- Kernel C: split-j flash PAM via MFMA ----------------
// grid = B * 64(i-tiles of 64) * 4(j-groups) = 512 blocks, 4 waves.
// wave w handles 16 queries (i0 = it*64 + w*16), j-range = jg*1024..+1024.
// Swapped PV: OutT[c][i] = sum_j V[c][j] * P^T[j][i] via mfma_16x16x32_bf16.
// Energies f32 VALU (d=4), exp f32, sumexp f32; P,V bf16 for MFMA only.
__global__ __launch_bounds__(256) void kflash(const float* __restrict__ qg,
    const float* __restrict__ kg, const short* __restrict__ vbf,
    float* __restrict__ part)
{
    int blk = blockIdx.x;
    int b = blk >> 8;
    int r = blk & 255;
    int it = r >> 2;             // 0..63
    int jg = r & 3;              // 0..3
    int w = threadIdx.x >> 6, lane = threadIdx.x & 63;
    int il = lane & 15;          // column (query) within tile
    int g  = lane >> 4;          // k-group 0..3
    int i0 = it*64 + w*16;

    const float* qb = qg + (size_t)b*C8*NN;
    const float* kb = kg + (size_t)b*C8*NN;
    const short* vb = vbf + (size_t)b*CC*NN;

    float qr[4];
    #pragma unroll
    for (int d = 0; d < 4; ++d) qr[d] = qb[(size_t)d*NN + i0 + il];

    f32x4 acc0 = {0.f,0.f,0.f,0.f};
    f32x4 acc1 = {0.f,0.f,0.f,0.f};
    float se = 0.f;

    const short* va0 = vb + (size_t)il*NN;        // A row c = il
    const short* va1 = vb + (size_t)(16+il)*NN;   // A row c = 16+il

    for (int jb = jg*1024; jb < jg*1024 + 1024; jb += 32) {
        int jo = jb + g*8;
        float e[8];
        #pragma unroll
        for (int t = 0; t < 8; ++t) e[t] = 0.f;
        #pragma unroll
        for (int d = 0; d < 4; ++d) {
            const float* kp = kb + (size_t)d*NN + jo;
            float4 k0 = *(const float4*)kp;
            float4 k1 = *(const float4*)(kp + 4);
            float qd = qr[d];
            e[0] += qd*k0.x; e[1] += qd*k0.y; e[2] += qd*k0.z; e[3] += qd*k0.w;
            e[4] += qd*k1.x; e[5] += qd*k1.y; e[6] += qd*k1.z; e[7] += qd*k1.w;
        }
        float p[8];
        #pragma unroll
        for (int t = 0; t < 8; ++t) p[t] = __expf(e[t]);
        se += ((p[0]+p[1])+(p[2]+p[3])) + ((p[4]+p[5])+(p[6]+p[7]));
        short8 bp;
        #pragma unroll
        for (int t = 0; t < 8; ++t) bp[t] = f2bf(p[t]);
        short8 a0 = *(const short8*)(va0 + jo);
        short8 a1 = *(const short8*)(va1 + jo);
        acc0 = __builtin_amdgcn_mfma_f32_16x16x32_bf16(a0, bp, acc0, 0, 0, 0);
        acc1 = __builtin_amdgcn_mfma_f32_16x16x32_bf16(a1, bp, acc1, 0, 0, 0);
    }

    // reduce sumexp across the 4 k-groups (lanes with same il)
    se += __shfl_xor(se, 16, 64);
    se += __shfl_xor(se, 32, 64);

    // write partials: part[b][jg][f][n], f=0..31 = c (unnormalized PV), f=32 = sumexp
    float* pb = part + ((size_t)(b*4 + jg)*33)*NN + i0 + il;
    #pragma unroll
    for (int rr = 0; rr < 4; ++rr) {
        pb[(size_t)(g*4 + rr)*NN]      = acc0[rr];
        pb[(size_t)(16 + g*4 + rr)*NN] = acc1[rr];
    }
    if (g == 0) pb[(size_t)32*NN] = se;
}

// ---------------- Kernel D: combine partials + output projection ----------------
__global__ __launch_bounds__(256) void kout(const float* __restrict__ part,
    const float* __restrict__ x, const float* __restrict__ wo,
    const float* __restrict__ bo, const float* __restrict__ gp,
    const float* __restrict__ wx, float* __restrict__ out)
{
    __shared__ float sw1[CC*CC], swx[CC*CC], sbo[CC];
    int blk = blockIdx.x;
    int b = blk >> 4;                   // 16 blocks per batch
    int n = (blk & 15)*256 + threadIdx.x;
    float g = gp[0];
    for (int i = threadIdx.x; i < CC*CC; i += 256) {
        int o = i >> 5, c2 = i & 31;
        sw1[i] = g * wo[o*64 + c2];
        swx[i] = wx[b*CC*CC + i];
    }
    if (threadIdx.x < CC) sbo[threadIdx.x] = bo[threadIdx.x];
    __syncthreads();

    const float* pb = part + (size_t)b*4*33*NN + n;
    float acc[CC]; float se = 0.f;
    #pragma unroll
    for (int c = 0; c < CC; ++c) acc[c] = 0.f;
    #pragma unroll
    for (int jg = 0; jg < 4; ++jg) {
        const float* p = pb + (size_t)jg*33*NN;
        #pragma unroll
        for (int f = 0; f < CC; ++f) acc[f] += p[(size_t)f*NN];
        se += p[(size_t)32*NN];
    }
    float inv = 1.f/se;
    float o_[CC];
    #pragma unroll
    for (int o = 0; o < CC; ++o) o_[o] = sbo[o];
    #pragma unroll
    for (int c = 0; c < CC; ++c) {
        float pc = acc[c]*inv;
        #pragma unroll
        for (int o = 0; o < CC; ++o) o_[o] += sw1[o*CC+c]*pc;
    }
    const float* xb = x + (size_t)b*CC*NN + n;
    #pragma unroll
    for (int d = 0; d < CC; ++d) {
        float xd = xb[(size_t)d*NN];
        #pragma unroll
        for (int o = 0; o < CC; ++o) o_[o] += swx[o*CC+d]*xd;
    }
    float* ob = out + (size_t)b*CC*NN + n;
    #pragma unroll
    for (int o = 0; o < CC; ++o) ob[(size_t)o*NN] = o_[o];
}

extern "C" void kernel_launch(void* const* d_in, const int* in_sizes, int n_in,
                              void* d_out, int out_size, void* d_ws, size_t ws_size,
                              hipStream_t stream)
{
    const float* x  = (const float*)d_in[0];
    const float* wq = (const float*)d_in[1];
    const float* bq = (const float*)d_in[2];
    const float* wk = (const float*)d_in[3];
    const float* bk = (const float*)d_in[4];
    const float* wv = (const float*)d_in[5];
    const float* bv = (const float*)d_in[6];
    const float* gp = (const float*)d_in[7];
    const float* gc = (const float*)d_in[8];
    const float* wo = (const float*)d_in[9];
    const float* bo = (const float*)d_in[10];

    float* ws   = (float*)d_ws;
    float* q    = ws;                  // B*C8*N = 32768 f
    float* k    = q + 32768;           // 32768 f
    short* vbf  = (short*)(k + 32768); // B*C*N = 262144 shorts = 131072 f
    float* eng  = k + 32768 + 131072;  // 2048 f
    float* wx   = eng + 2048;          // 2048 f
    float* part = wx + 2048;           // B*4*33*N = 1081344 f  (~5.1 MB total)

    kproj<<<32, 256, 0, stream>>>(x, wq, bq, wk, bk, wv, bv, q, k, vbf);
    keng<<<512, 256, 0, stream>>>(x, eng);
    kwx<<<BB, 256, 0, stream>>>(eng, wo, gc, wx);
    kflash<<<512, 256, 0, stream>>>(q, k, vbf, part);
    kout<<<32, 256, 0, stream>>>(part, x, wo, bo, gp, wx, (float*)d_out);
}

// Round 3
// 64.172 us; speedup vs baseline: 5.0757x; 1.0384x over previous
//
#include <hip/hip_runtime.h>
#include <hip/hip_bf16.h>
#include <math.h>

#define BB 2
#define CC 32
#define C8 4
#define NN 4096
#define JG 8          // j-split groups
#define JR (NN/JG)    // 512 keys per wave

typedef __attribute__((ext_vector_type(8))) short short8;
typedef __attribute__((ext_vector_type(4))) float f32x4;

static __device__ __forceinline__ short f2bf(float x) {
    return __builtin_bit_cast(short, __float2bfloat16(x));
}

// ---------------- K1: fused QKV projection (blocks 0..31) + CAM gram (blocks 32..543) ----
__global__ __launch_bounds__(256) void k1(const float* __restrict__ x,
    const float* __restrict__ wq, const float* __restrict__ bq,
    const float* __restrict__ wk, const float* __restrict__ bk,
    const float* __restrict__ wv, const float* __restrict__ bv,
    float* __restrict__ q, float* __restrict__ k, short* __restrict__ vbf,
    float* __restrict__ eng)
{
    if (blockIdx.x >= 32) {
        // ---- keng: one wave per (b,c,d) pair ----
        int w = threadIdx.x >> 6, lane = threadIdx.x & 63;
        int p = (blockIdx.x - 32)*4 + w;      // 0..2047
        int b = p >> 10, c = (p >> 5) & 31, d = p & 31;
        const float4* xc = (const float4*)(x + ((size_t)b*CC + c)*NN);
        const float4* xd = (const float4*)(x + ((size_t)b*CC + d)*NN);
        float s = 0.f;
        for (int t = lane; t < NN/4; t += 64) {
            float4 a = xc[t], bb = xd[t];
            s += a.x*bb.x + a.y*bb.y + a.z*bb.z + a.w*bb.w;
        }
        #pragma unroll
        for (int off = 32; off; off >>= 1) s += __shfl_down(s, off, 64);
        if (lane == 0) eng[p] = s;
        return;
    }
    // ---- kproj: thread = (b,n) ----
    __shared__ float swq[C8*CC], swk[C8*CC], swv[CC*CC], sbq[C8], sbk[C8], sbv[CC];
    int tid = threadIdx.x;
    for (int i = tid; i < C8*CC; i += 256) { swq[i] = wq[i]; swk[i] = wk[i]; }
    for (int i = tid; i < CC*CC; i += 256) swv[i] = wv[i];
    if (tid < C8) { sbq[tid] = bq[tid]; sbk[tid] = bk[tid]; }
    if (tid < CC) sbv[tid] = bv[tid];
    __syncthreads();
    int g = blockIdx.x*256 + tid;         // 0..8191
    int b = g >> 12; int n = g & (NN-1);
    const float* xb = x + (size_t)b*CC*NN + n;
    float xr[CC];
    #pragma unroll
    for (int c = 0; c < CC; ++c) xr[c] = xb[(size_t)c*NN];
    #pragma unroll
    for (int o = 0; o < C8; ++o) {
        float aq = sbq[o], ak = sbk[o];
        #pragma unroll
        for (int c = 0; c < CC; ++c) { aq += swq[o*CC+c]*xr[c]; ak += swk[o*CC+c]*xr[c]; }
        q[((size_t)b*C8+o)*NN + n] = aq;
        k[((size_t)b*C8+o)*NN + n] = ak;
    }
    #pragma unroll
    for (int o = 0; o < CC; ++o) {
        float av = sbv[o];
        #pragma unroll
        for (int c = 0; c < CC; ++c) av += swv[o*CC+c]*xr[c];
        vbf[((size_t)b*CC+o)*NN + n] = f2bf(av);
    }
}

// ---------------- flash helpers ----------------
struct KVb { float4 kA[4], kB[4]; short8 a0, a1; };

static __device__ __forceinline__ KVb ldkv(const float* __restrict__ kb,
    const short* __restrict__ va0, const short* __restrict__ va1, int jo)
{
    KVb r;
    #pragma unroll
    for (int d = 0; d < 4; ++d) {
        const float* kp = kb + (size_t)d*NN + jo;
        r.kA[d] = *(const float4*)kp;
        r.kB[d] = *(const float4*)(kp + 4);
    }
    r.a0 = *(const short8*)(va0 + jo);
    r.a1 = *(const short8*)(va1 + jo);
    return r;
}

static __device__ __forceinline__ void stepkv(const KVb& c, const float* qr,
    f32x4& acc0, f32x4& acc1, float& se)
{
    float e[8];
    #pragma unroll
    for (int t = 0; t < 8; ++t) e[t] = 0.f;
    #pragma unroll
    for (int d = 0; d < 4; ++d) {
        float qd = qr[d];
        e[0] += qd*c.kA[d].x; e[1] += qd*c.kA[d].y; e[2] += qd*c.kA[d].z; e[3] += qd*c.kA[d].w;
        e[4] += qd*c.kB[d].x; e[5] += qd*c.kB[d].y; e[6] += qd*c.kB[d].z; e[7] += qd*c.kB[d].w;
    }
    float p[8];
    #pragma unroll
    for (int t = 0; t < 8; ++t) p[t] = __expf(e[t]);
    se += ((p[0]+p[1])+(p[2]+p[3])) + ((p[4]+p[5])+(p[6]+p[7]));
    short8 bp;
    #pragma unroll
    for (int t = 0; t < 8; ++t) bp[t] = f2bf(p[t]);
    acc0 = __builtin_amdgcn_mfma_f32_16x16x32_bf16(c.a0, bp, acc0, 0, 0, 0);
    acc1 = __builtin_amdgcn_mfma_f32_16x16x32_bf16(c.a1, bp, acc1, 0, 0, 0);
}

// ---------------- K2: flash PAM partials (blocks 0..1023) + Wx fold (blocks 1024..1025) ----
__global__ __launch_bounds__(256, 4) void k2(const float* __restrict__ qg,
    const float* __restrict__ kg, const short* __restrict__ vbf,
    float* __restrict__ part,
    const float* __restrict__ eng, const float* __restrict__ wo,
    const float* __restrict__ gc, float* __restrict__ wx)
{
    if (blockIdx.x >= BB*512) {
        // ---- kwx: softmax(cattn) folded into Wx, one block per batch ----
        __shared__ float se_[CC*CC], sc[CC*CC];
        int b = blockIdx.x - BB*512, tid = threadIdx.x;
        for (int i = tid; i < CC*CC; i += 256) se_[i] = eng[b*CC*CC + i];
        __syncthreads();
        if (tid < CC) {
            float mn = se_[tid*CC];
            #pragma unroll
            for (int d = 1; d < CC; ++d) mn = fminf(mn, se_[tid*CC+d]);
            float pv[CC]; float s = 0.f;
            #pragma unroll
            for (int d = 0; d < CC; ++d) { pv[d] = __expf(mn - se_[tid*CC+d]); s += pv[d]; }
            float inv = 1.f/s;
            #pragma unroll
            for (int d = 0; d < CC; ++d) sc[tid*CC+d] = pv[d]*inv;
        }
        __syncthreads();
        float g = gc[0];
        for (int i = tid; i < CC*CC; i += 256) {
            int o = i >> 5, d = i & 31;
            float acc = wo[o*64 + d] + wo[o*64 + 32 + d];
            float t = 0.f;
            #pragma unroll
            for (int c2 = 0; c2 < CC; ++c2) t += wo[o*64 + 32 + c2] * sc[c2*CC + d];
            wx[b*CC*CC + i] = acc + g * t;
        }
        return;
    }
    // ---- flash: wave = 16 queries x 512 keys ----
    int blk = blockIdx.x;
    int b = blk >> 9;
    int r = blk & 511;
    int it = r >> 3;             // 0..63
    int jg = r & 7;              // 0..7
    int w = threadIdx.x >> 6, lane = threadIdx.x & 63;
    int il = lane & 15;          // query column in tile
    int g  = lane >> 4;          // k-group 0..3
    int i0 = it*64 + w*16;

    const float* qb = qg + (size_t)b*C8*NN;
    const float* kb = kg + (size_t)b*C8*NN;
    const short* vb = vbf + (size_t)b*CC*NN;

    float qr[4];
    #pragma unroll
    for (int d = 0; d < 4; ++d) qr[d] = qb[(size_t)d*NN + i0 + il];

    const short* va0 = vb + (size_t)il*NN;        // A row c = il
    const short* va1 = vb + (size_t)(16+il)*NN;   // A row c = 16+il

    f32x4 acc0 = {0.f,0.f,0.f,0.f};
    f32x4 acc1 = {0.f,0.f,0.f,0.f};
    float se = 0.f;
    int jbase = jg*JR + g*8;

    #pragma unroll 2
    for (int t = 0; t < JR/32; ++t) {
        KVb c = ldkv(kb, va0, va1, jbase + t*32);
        stepkv(c, qr, acc0, acc1, se);
    }

    // reduce sumexp across the 4 k-groups (lanes with same il)
    se += __shfl_xor(se, 16, 64);
    se += __shfl_xor(se, 32, 64);

    // partials: part[b][jg][f][n], f=0..31 = channel c (unnormalized PV), f=32 = sumexp
    float* pb = part + ((size_t)(b*JG + jg)*33)*NN + i0 + il;
    #pragma unroll
    for (int rr = 0; rr < 4; ++rr) {
        pb[(size_t)(g*4 + rr)*NN]      = acc0[rr];
        pb[(size_t)(16 + g*4 + rr)*NN] = acc1[rr];
    }
    if (g == 0) pb[(size_t)32*NN] = se;
}

// ---------------- K3: combine partials + output projection ----------------
__global__ __launch_bounds__(256) void kout(const float* __restrict__ part,
    const float* __restrict__ x, const float* __restrict__ wo,
    const float* __restrict__ bo, const float* __restrict__ gp,
    const float* __restrict__ wx, float* __restrict__ out)
{
    __shared__ float sw1[CC*CC], swx[CC*CC], sbo[CC];
    int blk = blockIdx.x;
    int b = blk >> 4;                   // 16 blocks per batch
    int n = (blk & 15)*256 + threadIdx.x;
    float g = gp[0];
    for (int i = threadIdx.x; i < CC*CC; i += 256) {
        int o = i >> 5, c2 = i & 31;
        sw1[i] = g * wo[o*64 + c2];
        swx[i] = wx[b*CC*CC + i];
    }
    if (threadIdx.x < CC) sbo[threadIdx.x] = bo[threadIdx.x];
    __syncthreads();

    const float* pb = part + (size_t)b*JG*33*NN + n;
    float acc[CC]; float se = 0.f;
    #pragma unroll
    for (int c = 0; c < CC; ++c) acc[c] = 0.f;
    #pragma unroll
    for (int jg = 0; jg < JG; ++jg) {
        const float* p = pb + (size_t)jg*33*NN;
        #pragma unroll
        for (int f = 0; f < CC; ++f) acc[f] += p[(size_t)f*NN];
        se += p[(size_t)32*NN];
    }
    float inv = 1.f/se;
    float o_[CC];
    #pragma unroll
    for (int o = 0; o < CC; ++o) o_[o] = sbo[o];
    #pragma unroll
    for (int c = 0; c < CC; ++c) {
        float pc = acc[c]*inv;
        #pragma unroll
        for (int o = 0; o < CC; ++o) o_[o] += sw1[o*CC+c]*pc;
    }
    const float* xb = x + (size_t)b*CC*NN + n;
    #pragma unroll
    for (int d = 0; d < CC; ++d) {
        float xd = xb[(size_t)d*NN];
        #pragma unroll
        for (int o = 0; o < CC; ++o) o_[o] += swx[o*CC+d]*xd;
    }
    float* ob = out + (size_t)b*CC*NN + n;
    #pragma unroll
    for (int o = 0; o < CC; ++o) ob[(size_t)o*NN] = o_[o];
}

extern "C" void kernel_launch(void* const* d_in, const int* in_sizes, int n_in,
                              void* d_out, int out_size, void* d_ws, size_t ws_size,
                              hipStream_t stream)
{
    const float* x  = (const float*)d_in[0];
    const float* wq = (const float*)d_in[1];
    const float* bq = (const float*)d_in[2];
    const float* wk = (const float*)d_in[3];
    const float* bk = (const float*)d_in[4];
    const float* wv = (const float*)d_in[5];
    const float* bv = (const float*)d_in[6];
    const float* gp = (const float*)d_in[7];
    const float* gc = (const float*)d_in[8];
    const float* wo = (const float*)d_in[9];
    const float* bo = (const float*)d_in[10];

    float* ws   = (float*)d_ws;
    float* q    = ws;                  // B*C8*N = 32768 f
    float* k    = q + 32768;           // 32768 f
    short* vbf  = (short*)(k + 32768); // B*C*N = 262144 shorts = 131072 f
    float* eng  = k + 32768 + 131072;  // 2048 f
    float* wx   = eng + 2048;          // 2048 f
    float* part = wx + 2048;           // B*JG*33*N = 2162688 f (~9.5 MB total)

    k1<<<544, 256, 0, stream>>>(x, wq, bq, wk, bk, wv, bv, q, k, vbf, eng);
    k2<<<BB*512 + BB, 256, 0, stream>>>(q, k, vbf, part, eng, wo, gc, wx);
    kout<<<32, 256, 0, stream>>>(part, x, wo, bo, gp, wx, (float*)d_out);
}

// Round 4
// 47.380 us; speedup vs baseline: 6.8746x; 1.3544x over previous
//
#include <hip/hip_runtime.h>
#include <hip/hip_bf16.h>
#include <math.h>

#define BB 2
#define CC 32
#define C8 4
#define NN 4096
#define JG 4          // j-split groups
#define JR (NN/JG)    // 1024 keys per block
#define LOG2E 1.4426950408889634f

typedef __attribute__((ext_vector_type(8))) short short8;
typedef __attribute__((ext_vector_type(4))) float f32x4;

static __device__ __forceinline__ short f2bf(float x) {
    return __builtin_bit_cast(short, __float2bfloat16(x));
}

// ---------------- K1: fused QKV projection (blocks 0..31) + CAM gram (blocks 32..543) ----
__global__ __launch_bounds__(256) void k1(const float* __restrict__ x,
    const float* __restrict__ wq, const float* __restrict__ bq,
    const float* __restrict__ wk, const float* __restrict__ bk,
    const float* __restrict__ wv, const float* __restrict__ bv,
    float* __restrict__ q, float* __restrict__ k, short* __restrict__ vbf,
    float* __restrict__ eng)
{
    if (blockIdx.x >= 32) {
        // ---- keng: one wave per (b,c,d) pair ----
        int w = threadIdx.x >> 6, lane = threadIdx.x & 63;
        int p = (blockIdx.x - 32)*4 + w;      // 0..2047
        int b = p >> 10, c = (p >> 5) & 31, d = p & 31;
        const float4* xc = (const float4*)(x + ((size_t)b*CC + c)*NN);
        const float4* xd = (const float4*)(x + ((size_t)b*CC + d)*NN);
        float s = 0.f;
        for (int t = lane; t < NN/4; t += 64) {
            float4 a = xc[t], bb = xd[t];
            s += a.x*bb.x + a.y*bb.y + a.z*bb.z + a.w*bb.w;
        }
        #pragma unroll
        for (int off = 32; off; off >>= 1) s += __shfl_down(s, off, 64);
        if (lane == 0) eng[p] = s;
        return;
    }
    // ---- kproj: thread = (b,n) ----
    __shared__ float swq[C8*CC], swk[C8*CC], swv[CC*CC], sbq[C8], sbk[C8], sbv[CC];
    int tid = threadIdx.x;
    for (int i = tid; i < C8*CC; i += 256) { swq[i] = wq[i]; swk[i] = wk[i]; }
    for (int i = tid; i < CC*CC; i += 256) swv[i] = wv[i];
    if (tid < C8) { sbq[tid] = bq[tid]; sbk[tid] = bk[tid]; }
    if (tid < CC) sbv[tid] = bv[tid];
    __syncthreads();
    int g = blockIdx.x*256 + tid;         // 0..8191
    int b = g >> 12; int n = g & (NN-1);
    const float* xb = x + (size_t)b*CC*NN + n;
    float xr[CC];
    #pragma unroll
    for (int c = 0; c < CC; ++c) xr[c] = xb[(size_t)c*NN];
    #pragma unroll
    for (int o = 0; o < C8; ++o) {
        float aq = sbq[o], ak = sbk[o];
        #pragma unroll
        for (int c = 0; c < CC; ++c) { aq += swq[o*CC+c]*xr[c]; ak += swk[o*CC+c]*xr[c]; }
        q[((size_t)b*C8+o)*NN + n] = aq;
        k[((size_t)b*C8+o)*NN + n] = ak;
    }
    #pragma unroll
    for (int o = 0; o < CC; ++o) {
        float av = sbv[o];
        #pragma unroll
        for (int c = 0; c < CC; ++c) av += swv[o*CC+c]*xr[c];
        vbf[((size_t)b*CC+o)*NN + n] = f2bf(av);
    }
}

// ---------------- K2: flash PAM partials (blocks 0..511) + Wx fold (blocks 512..513) ----
// Block = i-tile(64 queries) x jg-slab(1024 keys). K slab staged in LDS once.
// V loads: explicit depth-2 prefetch ring (only global loads in the loop).
__global__ __launch_bounds__(256, 2) void k2(const float* __restrict__ qg,
    const float* __restrict__ kg, const short* __restrict__ vbf,
    float* __restrict__ part,
    const float* __restrict__ eng, const float* __restrict__ wo,
    const float* __restrict__ gc, float* __restrict__ wx)
{
    if (blockIdx.x >= BB*64*JG) {
        // ---- kwx: softmax(cattn) folded into Wx, one block per batch ----
        __shared__ float se_[CC*CC], sc[CC*CC];
        int b = blockIdx.x - BB*64*JG, tid = threadIdx.x;
        for (int i = tid; i < CC*CC; i += 256) se_[i] = eng[b*CC*CC + i];
        __syncthreads();
        if (tid < CC) {
            float mn = se_[tid*CC];
            #pragma unroll
            for (int d = 1; d < CC; ++d) mn = fminf(mn, se_[tid*CC+d]);
            float pv[CC]; float s = 0.f;
            #pragma unroll
            for (int d = 0; d < CC; ++d) { pv[d] = __expf(mn - se_[tid*CC+d]); s += pv[d]; }
            float inv = 1.f/s;
            #pragma unroll
            for (int d = 0; d < CC; ++d) sc[tid*CC+d] = pv[d]*inv;
        }
        __syncthreads();
        float g = gc[0];
        for (int i = tid; i < CC*CC; i += 256) {
            int o = i >> 5, d = i & 31;
            float acc = wo[o*64 + d] + wo[o*64 + 32 + d];
            float t = 0.f;
            #pragma unroll
            for (int c2 = 0; c2 < CC; ++c2) t += wo[o*64 + 32 + c2] * sc[c2*CC + d];
            wx[b*CC*CC + i] = acc + g * t;
        }
        return;
    }

    __shared__ alignas(16) float kl[4*JR];     // 16 KB K slab [d][JR]

    int blk = blockIdx.x;
    int b = blk >> 8;            // 256 blocks per batch
    int r = blk & 255;
    int it = r >> 2;             // 0..63 i-tile
    int jg = r & (JG-1);         // 0..3

    const float* kb = kg + (size_t)b*C8*NN + jg*JR;
    {   // cooperative K staging: 1024 float4 rounds
        float4* kl4 = (float4*)kl;
        int tid = threadIdx.x;
        #pragma unroll
        for (int rr = 0; rr < 4; ++rr) {
            int idx = tid + rr*256;          // 0..1023
            int d = idx >> 8;                // [d][256 float4]
            int c4 = idx & 255;
            kl4[idx] = *(const float4*)(kb + (size_t)d*NN + c4*4);
        }
    }
    __syncthreads();

    int w = threadIdx.x >> 6, lane = threadIdx.x & 63;
    int il = lane & 15;          // query column in tile
    int g  = lane >> 4;          // k-group 0..3
    int i0 = it*64 + w*16;

    const float* qb = qg + (size_t)b*C8*NN;
    float qr[4];
    #pragma unroll
    for (int d = 0; d < 4; ++d) qr[d] = qb[(size_t)d*NN + i0 + il] * LOG2E;

    const short* vb  = vbf + (size_t)b*CC*NN + jg*JR;
    const short* va0 = vb + (size_t)il*NN;        // A row c = il
    const short* va1 = vb + (size_t)(16+il)*NN;   // A row c = 16+il
    int lc = g*8;                                  // lane col base within slab

    f32x4 acc0 = {0.f,0.f,0.f,0.f};
    f32x4 acc1 = {0.f,0.f,0.f,0.f};
    float se = 0.f;

    // depth-2 prefetch ring for V (overrun reads stay inside workspace)
    short8 cur0 = *(const short8*)(va0 + lc);
    short8 cur1 = *(const short8*)(va1 + lc);
    short8 nxt0 = *(const short8*)(va0 + lc + 32);
    short8 nxt1 = *(const short8*)(va1 + lc + 32);

    #pragma unroll 8
    for (int t = 0; t < JR/32; ++t) {
        short8 pf0 = *(const short8*)(va0 + lc + (t+2)*32);
        short8 pf1 = *(const short8*)(va1 + lc + (t+2)*32);
        int kc = lc + t*32;
        float e[8];
        #pragma unroll
        for (int tt = 0; tt < 8; ++tt) e[tt] = 0.f;
        #pragma unroll
        for (int d = 0; d < 4; ++d) {
            float4 kA = *(const float4*)(kl + d*JR + kc);
            float4 kB = *(const float4*)(kl + d*JR + kc + 4);
            float qd = qr[d];
            e[0] += qd*kA.x; e[1] += qd*kA.y; e[2] += qd*kA.z; e[3] += qd*kA.w;
            e[4] += qd*kB.x; e[5] += qd*kB.y; e[6] += qd*kB.z; e[7] += qd*kB.w;
        }
        float p[8];
        #pragma unroll
        for (int tt = 0; tt < 8; ++tt) p[tt] = exp2f(e[tt]);   // q pre-scaled by log2e
        se += ((p[0]+p[1])+(p[2]+p[3])) + ((p[4]+p[5])+(p[6]+p[7]));
        short8 bp;
        #pragma unroll
        for (int tt = 0; tt < 8; ++tt) bp[tt] = f2bf(p[tt]);
        acc0 = __builtin_amdgcn_mfma_f32_16x16x32_bf16(cur0, bp, acc0, 0, 0, 0);
        acc1 = __builtin_amdgcn_mfma_f32_16x16x32_bf16(cur1, bp, acc1, 0, 0, 0);
        cur0 = nxt0; cur1 = nxt1;
        nxt0 = pf0;  nxt1 = pf1;
    }

    // reduce sumexp across the 4 k-groups (lanes with same il)
    se += __shfl_xor(se, 16, 64);
    se += __shfl_xor(se, 32, 64);

    // partials: part[b][jg][f][n], f=0..31 = channel c (unnormalized PV), f=32 = sumexp
    float* pb = part + ((size_t)(b*JG + jg)*33)*NN + i0 + il;
    #pragma unroll
    for (int rr = 0; rr < 4; ++rr) {
        pb[(size_t)(g*4 + rr)*NN]      = acc0[rr];
        pb[(size_t)(16 + g*4 + rr)*NN] = acc1[rr];
    }
    if (g == 0) pb[(size_t)32*NN] = se;
}

// ---------------- K3: combine partials + output projection ----------------
__global__ __launch_bounds__(256) void kout(const float* __restrict__ part,
    const float* __restrict__ x, const float* __restrict__ wo,
    const float* __restrict__ bo, const float* __restrict__ gp,
    const float* __restrict__ wx, float* __restrict__ out)
{
    __shared__ float sw1[CC*CC], swx[CC*CC], sbo[CC];
    int blk = blockIdx.x;
    int b = blk >> 4;                   // 16 blocks per batch
    int n = (blk & 15)*256 + threadIdx.x;
    float g = gp[0];
    for (int i = threadIdx.x; i < CC*CC; i += 256) {
        int o = i >> 5, c2 = i & 31;
        sw1[i] = g * wo[o*64 + c2];
        swx[i] = wx[b*CC*CC + i];
    }
    if (threadIdx.x < CC) sbo[threadIdx.x] = bo[threadIdx.x];
    __syncthreads();

    const float* pb = part + (size_t)b*JG*33*NN + n;
    float acc[CC]; float se = 0.f;
    #pragma unroll
    for (int c = 0; c < CC; ++c) acc[c] = 0.f;
    #pragma unroll
    for (int jg = 0; jg < JG; ++jg) {
        const float* p = pb + (size_t)jg*33*NN;
        #pragma unroll
        for (int f = 0; f < CC; ++f) acc[f] += p[(size_t)f*NN];
        se += p[(size_t)32*NN];
    }
    float inv = 1.f/se;
    float o_[CC];
    #pragma unroll
    for (int o = 0; o < CC; ++o) o_[o] = sbo[o];
    #pragma unroll
    for (int c = 0; c < CC; ++c) {
        float pc = acc[c]*inv;
        #pragma unroll
        for (int o = 0; o < CC; ++o) o_[o] += sw1[o*CC+c]*pc;
    }
    const float* xb = x + (size_t)b*CC*NN + n;
    #pragma unroll
    for (int d = 0; d < CC; ++d) {
        float xd = xb[(size_t)d*NN];
        #pragma unroll
        for (int o = 0; o < CC; ++o) o_[o] += swx[o*CC+d]*xd;
    }
    float* ob = out + (size_t)b*CC*NN + n;
    #pragma unroll
    for (int o = 0; o < CC; ++o) ob[(size_t)o*NN] = o_[o];
}

extern "C" void kernel_launch(void* const* d_in, const int* in_sizes, int n_in,
                              void* d_out, int out_size, void* d_ws, size_t ws_size,
                              hipStream_t stream)
{
    const float* x  = (const float*)d_in[0];
    const float* wq = (const float*)d_in[1];
    const float* bq = (const float*)d_in[2];
    const float* wk = (const float*)d_in[3];
    const float* bk = (const float*)d_in[4];
    const float* wv = (const float*)d_in[5];
    const float* bv = (const float*)d_in[6];
    const float* gp = (const float*)d_in[7];
    const float* gc = (const float*)d_in[8];
    const float* wo = (const float*)d_in[9];
    const float* bo = (const float*)d_in[10];

    float* ws   = (float*)d_ws;
    float* q    = ws;                  // B*C8*N = 32768 f
    float* k    = q + 32768;           // 32768 f
    short* vbf  = (short*)(k + 32768); // B*C*N = 262144 shorts = 131072 f
    float* eng  = k + 32768 + 131072;  // 2048 f
    float* wx   = eng + 2048;          // 2048 f
    float* part = wx + 2048;           // B*JG*33*N = 1081344 f (~5.1 MB total)

    k1<<<544, 256, 0, stream>>>(x, wq, bq, wk, bk, wv, bv, q, k, vbf, eng);
    k2<<<BB*64*JG + BB, 256, 0, stream>>>(q, k, vbf, part, eng, wo, gc, wx);
    kout<<<32, 256, 0, stream>>>(part, x, wo, bo, gp, wx, (float*)d_out);
}